// Round 4
// baseline (519.339 us; speedup 1.0000x reference)
//
#include <hip/hip_runtime.h>
#include <hip/hip_bf16.h>
#include <stdint.h>

#define EPS 1e-3f

typedef __attribute__((ext_vector_type(8))) short bf16x8;
typedef __attribute__((ext_vector_type(4))) float f32x4;

__device__ inline uint32_t pk2(float a, float b) {
    __hip_bfloat162 p;
    p.x = __float2bfloat16(a);
    p.y = __float2bfloat16(b);
    return *(uint32_t*)&p;
}

// ---------------------------------------------------------------------------
// k0a: small preps.
//  W1t[f][K'] = bf16(W1[c][k*64+f]),  K' = k*64+c           (12288 elems)
//  Abf[(kb*64+fo)*8+j] = bf16(Wt[dt][fi][fo]), kb*8+j=dt*64+fi (36864 elems)
//  csA_g[k][t*25+w] = sum_v A[k][t][v][w]                    (22500 floats)
// ---------------------------------------------------------------------------
__global__ __launch_bounds__(256) void k0_prep_small(
    const float* __restrict__ W1, const float* __restrict__ Wt,
    const float* __restrict__ A,
    uint16_t* __restrict__ W1t, uint16_t* __restrict__ Abf,
    float* __restrict__ csA_g)
{
    int i = blockIdx.x * 256 + threadIdx.x;
    if (i < 12288) {
        int f = i / 192, Kp = i % 192, k = Kp >> 6, c = Kp & 63;
        __hip_bfloat16 b = __float2bfloat16(W1[c * 192 + k * 64 + f]);
        W1t[i] = *(uint16_t*)&b;
    } else if (i < 49152) {
        int j = i - 12288;
        int jj = j & 7, fo = (j >> 3) & 63, kb = j >> 9;
        int kk = kb * 8 + jj, dt = kk >> 6, fi = kk & 63;
        __hip_bfloat16 b = __float2bfloat16(Wt[(dt * 64 + fi) * 64 + fo]);
        Abf[j] = *(uint16_t*)&b;
    } else if (i < 71652) {
        int j = i - 49152;
        int k = j / 7500, r = j % 7500;
        int t = r / 25, w = r % 25;
        float s = 0.f;
        for (int v = 0; v < 25; ++v)
            s += A[((k * 300 + t) * 25 + v) * 25 + w];
        csA_g[j] = s;
    }
}

// ---------------------------------------------------------------------------
// k0b: At_g[k][t][w32][v32] = bf16(A[k][t][v][w]), zero outside v<25,w<25.
// ---------------------------------------------------------------------------
__global__ __launch_bounds__(256) void k0_prep_At(
    const float* __restrict__ A, uint16_t* __restrict__ At_g)
{
    int i = blockIdx.x * 256 + threadIdx.x;
    if (i < 921600) {
        int v = i & 31, w = (i >> 5) & 31, rest = i >> 10;
        int t = rest % 300, k = rest / 300;
        float val = 0.f;
        if (v < 25 && w < 25)
            val = A[((k * 300 + t) * 25 + v) * 25 + w];
        __hip_bfloat16 b = __float2bfloat16(val);
        At_g[i] = *(uint16_t*)&b;
    }
}

// ---------------------------------------------------------------------------
// k1_fused v2: t-tile = 4, 4 waves, ~60.5 KB LDS -> 2 blocks/CU.
//  phase A: coalesced stage of x[n,:,t0*25..t0*25+100) -> bf16 LDS slots
//           pre-shaped for MFMA A-frags (slot = 16B = one lane's k-octet).
//  phase B (per wave, t = t0+wv): GEMM-u  u[c][(k,w)] = sum_v x*A_t -> U LDS
//  phase C: GEMM-z  z[f][col] = W1t . U  -> bias(csA)+BN1+ReLU -> h2 bf16.
// LDS map (bytes): U 0..43007 (112 rows x 384); x-slots 43008..59391;
//                  csA 59392..60591; s1 60592; b1n 60848; b1 61104..61871.
// ---------------------------------------------------------------------------
#define K1_SMEM 61872
#define XBASE 43008
__global__ __launch_bounds__(256) void k1_fused(
    const float* __restrict__ x, const uint16_t* __restrict__ At_g,
    const uint16_t* __restrict__ W1t, const float* __restrict__ csA_g,
    const float* __restrict__ b1,
    const float* __restrict__ gamma1, const float* __restrict__ beta1,
    const float* __restrict__ mean1, const float* __restrict__ var1,
    uint32_t* __restrict__ h2u)
{
    extern __shared__ __align__(16) char smem[];
    float* csA_s = (float*)(smem + 59392);
    float* s1s   = (float*)(smem + 60592);
    float* b1ns  = (float*)(smem + 60848);
    float* b1s   = (float*)(smem + 61104);

    const int t0   = blockIdx.x * 4;
    const int n    = blockIdx.y;
    const int tid  = threadIdx.x;
    const int lane = tid & 63, wv = tid >> 6;
    const int l15  = lane & 15, g = lane >> 4;

    // ---- preload B-frags for GEMM-u (global, L2-resident) ----
    const int tw = t0 + wv;
    bf16x8 bfr[6];
    #pragma unroll
    for (int nf = 0; nf < 6; ++nf) {
        const int col = nf * 16 + l15;
        const int k = col >> 5, w = col & 31;
        bfr[nf] = *(const bf16x8*)(At_g + (((k * 300 + tw) * 32 + w) * 32 + g * 8));
    }

    // ---- stage x tile: coalesced fp32 reads -> bf16 swizzled slots ----
    const float* xn = x + (size_t)n * 480000;
    for (int it = tid; it < 3328; it += 256) {
        const int c = it / 52;
        const int r = it % 52;
        const int trel = r / 13, vp = r % 13;
        const int v = vp * 2;
        const float* p = xn + c * 7500 + (t0 + trel) * 25 + v;
        const int slot = XBASE + (((((v >> 3) * 64 + c) * 4 + trel) * 16) ^ ((c & 7) << 4));
        if (vp < 12) {
            *(uint32_t*)(smem + slot + ((v & 7) << 1)) = pk2(p[0], p[1]);
        } else {            // v = 24: real value + explicit zero padding v=25..31
            *(uint32_t*)(smem + slot + 0)  = pk2(p[0], 0.f);
            *(uint32_t*)(smem + slot + 4)  = 0u;
            *(uint32_t*)(smem + slot + 8)  = 0u;
            *(uint32_t*)(smem + slot + 12) = 0u;
        }
    }
    // ---- epilogue constants ----
    for (int i = tid; i < 300; i += 256) {
        int k = i / 100, cr = i % 100;
        csA_s[i] = csA_g[k * 7500 + t0 * 25 + cr];
    }
    if (tid < 64) {
        float rs = rsqrtf(var1[tid] + EPS);
        s1s[tid]  = gamma1[tid] * rs;
        b1ns[tid] = beta1[tid] - gamma1[tid] * mean1[tid] * rs;
    }
    if (tid >= 64 && tid < 256) b1s[tid - 64] = b1[tid - 64];
    __syncthreads();

    // ---- GEMM-u (one t per wave): a-frags from x-LDS ----
    bf16x8 a[4];
    #pragma unroll
    for (int mf = 0; mf < 4; ++mf) {
        const int c = l15 + 16 * mf;
        const int sb = XBASE + ((((g * 64 + c) * 4 + wv) * 16) ^ ((c & 7) << 4));
        a[mf] = *(const bf16x8*)(smem + sb);
    }

    f32x4 acc[4][6];
    #pragma unroll
    for (int mf = 0; mf < 4; ++mf)
        #pragma unroll
        for (int nf = 0; nf < 6; ++nf)
            acc[mf][nf] = (f32x4){0.f, 0.f, 0.f, 0.f};

    #pragma unroll
    for (int nf = 0; nf < 6; ++nf) {
        acc[0][nf] = __builtin_amdgcn_mfma_f32_16x16x32_bf16(a[0], bfr[nf], acc[0][nf], 0, 0, 0);
        acc[1][nf] = __builtin_amdgcn_mfma_f32_16x16x32_bf16(a[1], bfr[nf], acc[1][nf], 0, 0, 0);
        acc[2][nf] = __builtin_amdgcn_mfma_f32_16x16x32_bf16(a[2], bfr[nf], acc[2][nf], 0, 0, 0);
        acc[3][nf] = __builtin_amdgcn_mfma_f32_16x16x32_bf16(a[3], bfr[nf], acc[3][nf], 0, 0, 0);
    }

    // ---- write U rows (colrow = wv*25+w), swizzled ----
    #pragma unroll
    for (int nf = 0; nf < 6; ++nf) {
        const int col = nf * 16 + l15;
        const int k = col >> 5, w = col & 31;
        if (w < 25) {
            const int colrow = wv * 25 + w;
            const int sw = (w & 7) << 4;
            #pragma unroll
            for (int mf = 0; mf < 4; ++mf) {
                const int c0 = mf * 16 + g * 4;
                const int off = colrow * 384 + (((k * 64 + c0) * 2) ^ sw);
                uint2 val;
                val.x = pk2(acc[mf][nf][0], acc[mf][nf][1]);
                val.y = pk2(acc[mf][nf][2], acc[mf][nf][3]);
                *(uint2*)(smem + off) = val;
            }
        }
    }
    __syncthreads();

    // ---- GEMM-z: frags fr = wv, wv+4 (if <7) ----
    int colv[2], coladdr[2], swz[2], nq = (wv < 3) ? 2 : 1;
    #pragma unroll
    for (int q = 0; q < 2; ++q) {
        int fr = wv + 4 * q;
        int col = fr * 16 + l15;
        colv[q] = col;
        coladdr[q] = col * 384;
        swz[q] = ((col % 25) & 7) << 4;
    }

    f32x4 accz[4][2];
    #pragma unroll
    for (int mf = 0; mf < 4; ++mf)
        #pragma unroll
        for (int q = 0; q < 2; ++q)
            accz[mf][q] = (f32x4){0.f, 0.f, 0.f, 0.f};

    for (int kb = 0; kb < 6; ++kb) {
        bf16x8 az[4];
        #pragma unroll
        for (int mf = 0; mf < 4; ++mf)
            az[mf] = *(const bf16x8*)(W1t + (l15 + 16 * mf) * 192 + kb * 32 + g * 8);
        #pragma unroll
        for (int q = 0; q < 2; ++q) {
            if (q < nq) {
                bf16x8 b = *(const bf16x8*)(smem + coladdr[q] + ((kb * 64 + g * 16) ^ swz[q]));
                accz[0][q] = __builtin_amdgcn_mfma_f32_16x16x32_bf16(az[0], b, accz[0][q], 0, 0, 0);
                accz[1][q] = __builtin_amdgcn_mfma_f32_16x16x32_bf16(az[1], b, accz[1][q], 0, 0, 0);
                accz[2][q] = __builtin_amdgcn_mfma_f32_16x16x32_bf16(az[2], b, accz[2][q], 0, 0, 0);
                accz[3][q] = __builtin_amdgcn_mfma_f32_16x16x32_bf16(az[3], b, accz[3][q], 0, 0, 0);
            }
        }
    }

    // ---- epilogue: +bias(csA), BN1, ReLU, pack bf16, store h2 ----
    const uint32_t hbase = (uint32_t)(n * 300 + t0) * 800;
    #pragma unroll
    for (int q = 0; q < 2; ++q) {
        if (q < nq) {
            const int col = colv[q];
            if (col < 100) {
                const int trel = col / 25, w = col - trel * 25;
                const float cs0 = csA_s[col];
                const float cs1 = csA_s[100 + col];
                const float cs2 = csA_s[200 + col];
                const uint32_t rowbase = hbase + trel * 800 + w * 32;
                #pragma unroll
                for (int mf = 0; mf < 4; ++mf) {
                    const int f0 = mf * 16 + g * 4;
                    float zz[4];
                    #pragma unroll
                    for (int rg = 0; rg < 4; ++rg) {
                        const int f = f0 + rg;
                        float z = accz[mf][q][rg]
                                + b1s[f] * cs0 + b1s[64 + f] * cs1 + b1s[128 + f] * cs2;
                        z = z * s1s[f] + b1ns[f];
                        zz[rg] = fmaxf(z, 0.f);
                    }
                    uint2 st;
                    st.x = pk2(zz[0], zz[1]);
                    st.y = pk2(zz[2], zz[3]);
                    *(uint2*)(h2u + rowbase + (f0 >> 1)) = st;
                }
            }
        }
    }
}

// ---------------------------------------------------------------------------
// k2: temporal conv MFMA GEMM (M=64 fo, K=576, N=400 cols/block) + bias + BN2
//     + residual + ReLU.  Wt frags direct from global (L2); LDS = h tile only.
// ---------------------------------------------------------------------------
#define K2_SMEM 77312
__global__ __launch_bounds__(256) void k2_mfma(
    const char* __restrict__ h2b,     // bf16 bytes [n][t][w][f]
    const uint16_t* __restrict__ Abf, // Wt bf16, k0 layout
    const float* __restrict__ bt,
    const float* __restrict__ gamma2, const float* __restrict__ beta2,
    const float* __restrict__ mean2,  const float* __restrict__ var2,
    const float* __restrict__ x,      // residual
    float* __restrict__ out)
{
    extern __shared__ __align__(16) char smem2[];
    char*  lds_h = smem2;              // 76800 B
    float* s2s   = (float*)(smem2 + 76800);
    float* b2s   = s2s + 64;

    const int t0  = blockIdx.x * 16;
    const int n   = blockIdx.y;
    const int tid = threadIdx.x;

    if (tid < 64) {
        float rs = rsqrtf(var2[tid] + EPS);
        float s  = gamma2[tid] * rs;
        s2s[tid] = s;
        b2s[tid] = beta2[tid] - gamma2[tid] * mean2[tid] * rs + bt[tid] * s;
    }

    // ---- stage h tile (24 t-rows with halo), swizzled ----
    const size_t hn = (size_t)n * 300 * 3200;
    for (int c = tid; c < 4800; c += 256) {
        int rr = c >> 3, c8 = c & 7;
        int trow = rr / 25;
        int w = rr - trow * 25;
        int tg = t0 - 4 + trow;
        int4 v = make_int4(0, 0, 0, 0);
        if (tg >= 0 && tg < 300)
            v = *(const int4*)(h2b + hn + (size_t)tg * 3200 + w * 128 + (c8 << 4));
        int s = c << 4;
        *(int4*)(lds_h + (s ^ (((s >> 7) & 7) << 4))) = v;
    }
    __syncthreads();

    const int wv = tid >> 6, lane = tid & 63;
    const int l15 = lane & 15, g = lane >> 4;
    const int colbase = wv * 112;
    const int nfr = (wv == 3) ? 4 : 7;

    f32x4 acc[4][7];
    #pragma unroll
    for (int mf = 0; mf < 4; ++mf)
        #pragma unroll
        for (int nf = 0; nf < 7; ++nf)
            acc[mf][nf] = (f32x4){0.f, 0.f, 0.f, 0.f};

    for (int kk = 0; kk < 18; ++kk) {
        const int dt   = kk >> 1;
        const int half = (kk & 1) << 6;
        const int kb   = kk * 4 + g;
        bf16x8 a[4];
        #pragma unroll
        for (int mf = 0; mf < 4; ++mf)
            a[mf] = *(const bf16x8*)(Abf + (kb * 64 + l15 + mf * 16) * 8);
        #pragma unroll
        for (int nf = 0; nf < 7; ++nf) {
            if (nf < nfr) {
                int r = colbase + (nf << 4) + l15 + 25 * dt;
                int s = (r << 7) + half + (g << 4);
                bf16x8 b = *(const bf16x8*)(lds_h + (s ^ ((r & 7) << 4)));
                acc[0][nf] = __builtin_amdgcn_mfma_f32_16x16x32_bf16(a[0], b, acc[0][nf], 0, 0, 0);
                acc[1][nf] = __builtin_amdgcn_mfma_f32_16x16x32_bf16(a[1], b, acc[1][nf], 0, 0, 0);
                acc[2][nf] = __builtin_amdgcn_mfma_f32_16x16x32_bf16(a[2], b, acc[2][nf], 0, 0, 0);
                acc[3][nf] = __builtin_amdgcn_mfma_f32_16x16x32_bf16(a[3], b, acc[3][nf], 0, 0, 0);
            }
        }
    }

    const size_t outn = (size_t)n * 480000;
    #pragma unroll
    for (int mf = 0; mf < 4; ++mf) {
        #pragma unroll
        for (int nf = 0; nf < 7; ++nf) {
            if (nf < nfr) {
                int col  = colbase + (nf << 4) + l15;
                int gcol = t0 * 25 + col;
                if (gcol < 7500) {
                    #pragma unroll
                    for (int reg = 0; reg < 4; ++reg) {
                        int fo = (mf << 4) + (g << 2) + reg;
                        size_t ga = outn + (size_t)fo * 7500 + gcol;
                        float val = acc[mf][nf][reg] * s2s[fo] + b2s[fo];
                        out[ga] = fmaxf(val + x[ga], 0.f);
                    }
                }
            }
        }
    }
}

// ---------------------------------------------------------------------------
extern "C" void kernel_launch(void* const* d_in, const int* in_sizes, int n_in,
                              void* d_out, int out_size, void* d_ws, size_t ws_size,
                              hipStream_t stream) {
    const float* x      = (const float*)d_in[0];
    const float* W1     = (const float*)d_in[1];
    const float* b1     = (const float*)d_in[2];
    const float* A      = (const float*)d_in[3];
    const float* gamma1 = (const float*)d_in[4];
    const float* beta1  = (const float*)d_in[5];
    const float* mean1  = (const float*)d_in[6];
    const float* var1   = (const float*)d_in[7];
    const float* Wt     = (const float*)d_in[8];
    const float* bt     = (const float*)d_in[9];
    const float* gamma2 = (const float*)d_in[10];
    const float* beta2  = (const float*)d_in[11];
    const float* mean2  = (const float*)d_in[12];
    const float* var2   = (const float*)d_in[13];
    float* out = (float*)d_out;

    // ws layout (bytes):
    //   h2   : 0          .. 61,440,000   bf16 [64][300][25][64]
    //   At_g : 61,440,000 .. 63,283,200   bf16 [3][300][32][32]
    //   W1t  : 63,283,200 .. 63,307,776   bf16 [64][192]
    //   Abf  : 63,307,776 .. 63,381,504   bf16 Wt frags
    //   csA_g: 63,381,504 .. 63,471,504   f32  [3][7500]
    char* ws = (char*)d_ws;
    uint32_t* h2u   = (uint32_t*)ws;
    char*     h2b   = ws;
    uint16_t* At_g  = (uint16_t*)(ws + 61440000);
    uint16_t* W1t   = (uint16_t*)(ws + 63283200);
    uint16_t* Abf   = (uint16_t*)(ws + 63307776);
    float*    csA_g = (float*)   (ws + 63381504);

    hipFuncSetAttribute((const void*)k1_fused,
                        hipFuncAttributeMaxDynamicSharedMemorySize, K1_SMEM);
    hipFuncSetAttribute((const void*)k2_mfma,
                        hipFuncAttributeMaxDynamicSharedMemorySize, K2_SMEM);

    k0_prep_small<<<280, 256, 0, stream>>>(W1, Wt, A, W1t, Abf, csA_g);
    k0_prep_At<<<3600, 256, 0, stream>>>(A, At_g);
    k1_fused<<<dim3(75, 64), 256, K1_SMEM, stream>>>(
        x, At_g, W1t, csA_g, b1, gamma1, beta1, mean1, var1, h2u);
    k2_mfma<<<dim3(19, 64), 256, K2_SMEM, stream>>>(
        h2b, Abf, bt, gamma2, beta2, mean2, var2, x, out);
}

// Round 6
// 438.469 us; speedup vs baseline: 1.1844x; 1.1844x over previous
//
#include <hip/hip_runtime.h>
#include <hip/hip_bf16.h>
#include <stdint.h>

#define EPS 1e-3f

typedef __attribute__((ext_vector_type(8))) short bf16x8;
typedef __attribute__((ext_vector_type(4))) float f32x4;

__device__ inline uint32_t pk2(float a, float b) {
    __hip_bfloat162 p;
    p.x = __float2bfloat16(a);
    p.y = __float2bfloat16(b);
    return *(uint32_t*)&p;
}

// ---------------------------------------------------------------------------
// k0a: small preps.
//  W1t[f][K'] = bf16(W1[c][k*64+f]),  K' = k*64+c           (12288 elems)
//  Abf[(kb*64+fo)*8+j] = bf16(Wt[dt][fi][fo]), kb*8+j=dt*64+fi (36864 elems)
//  csA_g[k][t*25+w] = sum_v A[k][t][v][w]                    (22500 floats)
// ---------------------------------------------------------------------------
__global__ __launch_bounds__(256) void k0_prep_small(
    const float* __restrict__ W1, const float* __restrict__ Wt,
    const float* __restrict__ A,
    uint16_t* __restrict__ W1t, uint16_t* __restrict__ Abf,
    float* __restrict__ csA_g)
{
    int i = blockIdx.x * 256 + threadIdx.x;
    if (i < 12288) {
        int f = i / 192, Kp = i % 192, k = Kp >> 6, c = Kp & 63;
        __hip_bfloat16 b = __float2bfloat16(W1[c * 192 + k * 64 + f]);
        W1t[i] = *(uint16_t*)&b;
    } else if (i < 49152) {
        int j = i - 12288;
        int jj = j & 7, fo = (j >> 3) & 63, kb = j >> 9;
        int kk = kb * 8 + jj, dt = kk >> 6, fi = kk & 63;
        __hip_bfloat16 b = __float2bfloat16(Wt[(dt * 64 + fi) * 64 + fo]);
        Abf[j] = *(uint16_t*)&b;
    } else if (i < 71652) {
        int j = i - 49152;
        int k = j / 7500, r = j % 7500;
        int t = r / 25, w = r % 25;
        float s = 0.f;
        for (int v = 0; v < 25; ++v)
            s += A[((k * 300 + t) * 25 + v) * 25 + w];
        csA_g[j] = s;
    }
}

// ---------------------------------------------------------------------------
// k0b: At_g[k][t][w32][v32] = bf16(A[k][t][v][w]), zero outside v<25,w<25.
// ---------------------------------------------------------------------------
__global__ __launch_bounds__(256) void k0_prep_At(
    const float* __restrict__ A, uint16_t* __restrict__ At_g)
{
    int i = blockIdx.x * 256 + threadIdx.x;
    if (i < 921600) {
        int v = i & 31, w = (i >> 5) & 31, rest = i >> 10;
        int t = rest % 300, k = rest / 300;
        float val = 0.f;
        if (v < 25 && w < 25)
            val = A[((k * 300 + t) * 25 + v) * 25 + w];
        __hip_bfloat16 b = __float2bfloat16(val);
        At_g[i] = *(uint16_t*)&b;
    }
}

// ---------------------------------------------------------------------------
// k1_fused v3: t-tile = 4, 4 waves, 39,680 B LDS -> 4 blocks/CU (4 waves/SIMD).
//  GEMM-u A-frags loaded DIRECTLY from global x (scalar dwords, L1-shared
//  rows) -- no x staging. csA read directly from global in epilogue.
//  phase B (per wave, t = t0+wv): GEMM-u  u[c][(k,w)] = sum_v x*A_t -> U LDS
//  phase C: GEMM-z  z[f][col] = W1t . U  -> bias(csA)+BN1+ReLU -> h2 bf16.
// LDS map (bytes): U 0..38399 (100 rows x 384); s1 38400; b1n 38656;
//                  b1 38912..39679.
// ---------------------------------------------------------------------------
#define K1_SMEM 39680
__global__ __launch_bounds__(256, 4) void k1_fused(
    const float* __restrict__ x, const uint16_t* __restrict__ At_g,
    const uint16_t* __restrict__ W1t, const float* __restrict__ csA_g,
    const float* __restrict__ b1,
    const float* __restrict__ gamma1, const float* __restrict__ beta1,
    const float* __restrict__ mean1, const float* __restrict__ var1,
    uint32_t* __restrict__ h2u)
{
    extern __shared__ __align__(16) char smem[];
    float* s1s   = (float*)(smem + 38400);
    float* b1ns  = (float*)(smem + 38656);
    float* b1s   = (float*)(smem + 38912);

    const int t0   = blockIdx.x * 4;
    const int n    = blockIdx.y;
    const int tid  = threadIdx.x;
    const int lane = tid & 63, wv = tid >> 6;
    const int l15  = lane & 15, g = lane >> 4;
    const int t    = t0 + wv;                 // 75*4 = 300: no tail

    // ---- B-frags for GEMM-u (global, L2-resident) ----
    bf16x8 bfr[6];
    #pragma unroll
    for (int nf = 0; nf < 6; ++nf) {
        const int col = nf * 16 + l15;
        const int k = col >> 5, w = col & 31;
        bfr[nf] = *(const bf16x8*)(At_g + (((k * 300 + t) * 32 + w) * 32 + g * 8));
    }

    // ---- A-frags directly from x: lane reads x[n, c, t, g*8 .. g*8+7] ----
    const float* xb = x + (size_t)n * 480000 + t * 25;
    bf16x8 a[4];
    #pragma unroll
    for (int mf = 0; mf < 4; ++mf) {
        const int c = l15 + 16 * mf;
        const float* xr = xb + (size_t)c * 7500;
        union { bf16x8 v; uint32_t u[4]; } ua;
        if (g < 3) {
            const float* p = xr + g * 8;
            ua.u[0] = pk2(p[0], p[1]);
            ua.u[1] = pk2(p[2], p[3]);
            ua.u[2] = pk2(p[4], p[5]);
            ua.u[3] = pk2(p[6], p[7]);
        } else {            // v = 24 real; v = 25..31 zero (B rows zeroed too)
            ua.u[0] = pk2(xr[24], 0.f);
            ua.u[1] = 0; ua.u[2] = 0; ua.u[3] = 0;
        }
        a[mf] = ua.v;
    }

    // ---- epilogue constants (one-time, tiny) ----
    if (tid < 64) {
        float rs = rsqrtf(var1[tid] + EPS);
        s1s[tid]  = gamma1[tid] * rs;
        b1ns[tid] = beta1[tid] - gamma1[tid] * mean1[tid] * rs;
    }
    if (tid >= 64 && tid < 256) b1s[tid - 64] = b1[tid - 64];

    // ---- GEMM-u (one t per wave) ----
    f32x4 acc[4][6];
    #pragma unroll
    for (int mf = 0; mf < 4; ++mf)
        #pragma unroll
        for (int nf = 0; nf < 6; ++nf)
            acc[mf][nf] = (f32x4){0.f, 0.f, 0.f, 0.f};

    #pragma unroll
    for (int nf = 0; nf < 6; ++nf) {
        acc[0][nf] = __builtin_amdgcn_mfma_f32_16x16x32_bf16(a[0], bfr[nf], acc[0][nf], 0, 0, 0);
        acc[1][nf] = __builtin_amdgcn_mfma_f32_16x16x32_bf16(a[1], bfr[nf], acc[1][nf], 0, 0, 0);
        acc[2][nf] = __builtin_amdgcn_mfma_f32_16x16x32_bf16(a[2], bfr[nf], acc[2][nf], 0, 0, 0);
        acc[3][nf] = __builtin_amdgcn_mfma_f32_16x16x32_bf16(a[3], bfr[nf], acc[3][nf], 0, 0, 0);
    }

    // ---- write U rows (colrow = wv*25+w), swizzled ----
    #pragma unroll
    for (int nf = 0; nf < 6; ++nf) {
        const int col = nf * 16 + l15;
        const int k = col >> 5, w = col & 31;
        if (w < 25) {
            const int colrow = wv * 25 + w;
            const int sw = (w & 7) << 4;
            #pragma unroll
            for (int mf = 0; mf < 4; ++mf) {
                const int c0 = mf * 16 + g * 4;
                const int off = colrow * 384 + (((k * 64 + c0) * 2) ^ sw);
                uint2 val;
                val.x = pk2(acc[mf][nf][0], acc[mf][nf][1]);
                val.y = pk2(acc[mf][nf][2], acc[mf][nf][3]);
                *(uint2*)(smem + off) = val;
            }
        }
    }
    __syncthreads();

    // ---- GEMM-z: frags fr = wv, wv+4 (7 frags over 4 waves) ----
    int colv[2], coladdr[2], swz[2];
    const int nq = (wv < 3) ? 2 : 1;
    #pragma unroll
    for (int q = 0; q < 2; ++q) {
        int fr  = wv + 4 * q;
        int col = fr * 16 + l15;
        colv[q] = col;
        int colc = (col < 100) ? col : 99;    // clamp: keep ds_read in U region
        coladdr[q] = colc * 384;
        swz[q] = ((colc % 25) & 7) << 4;
    }

    f32x4 accz[4][2];
    #pragma unroll
    for (int mf = 0; mf < 4; ++mf)
        #pragma unroll
        for (int q = 0; q < 2; ++q)
            accz[mf][q] = (f32x4){0.f, 0.f, 0.f, 0.f};

    #pragma unroll
    for (int kb = 0; kb < 6; ++kb) {
        bf16x8 az[4];
        #pragma unroll
        for (int mf = 0; mf < 4; ++mf)
            az[mf] = *(const bf16x8*)(W1t + (l15 + 16 * mf) * 192 + kb * 32 + g * 8);
        #pragma unroll
        for (int q = 0; q < 2; ++q) {
            if (q < nq) {
                bf16x8 b = *(const bf16x8*)(smem + coladdr[q] + ((kb * 64 + g * 16) ^ swz[q]));
                accz[0][q] = __builtin_amdgcn_mfma_f32_16x16x32_bf16(az[0], b, accz[0][q], 0, 0, 0);
                accz[1][q] = __builtin_amdgcn_mfma_f32_16x16x32_bf16(az[1], b, accz[1][q], 0, 0, 0);
                accz[2][q] = __builtin_amdgcn_mfma_f32_16x16x32_bf16(az[2], b, accz[2][q], 0, 0, 0);
                accz[3][q] = __builtin_amdgcn_mfma_f32_16x16x32_bf16(az[3], b, accz[3][q], 0, 0, 0);
            }
        }
    }

    // ---- epilogue: +bias(csA direct from L2), BN1, ReLU, pack, store h2 ----
    const uint32_t hbase = (uint32_t)(n * 300 + t0) * 800;
    const int csbase = t0 * 25;
    #pragma unroll
    for (int q = 0; q < 2; ++q) {
        if (q < nq) {
            const int col = colv[q];
            if (col < 100) {
                const int trel = col / 25, w = col - trel * 25;
                const float cs0 = csA_g[csbase + col];
                const float cs1 = csA_g[7500 + csbase + col];
                const float cs2 = csA_g[15000 + csbase + col];
                const uint32_t rowbase = hbase + trel * 800 + w * 32;
                #pragma unroll
                for (int mf = 0; mf < 4; ++mf) {
                    const int f0 = mf * 16 + g * 4;
                    float zz[4];
                    #pragma unroll
                    for (int rg = 0; rg < 4; ++rg) {
                        const int f = f0 + rg;
                        float z = accz[mf][q][rg]
                                + b1s[f] * cs0 + b1s[64 + f] * cs1 + b1s[128 + f] * cs2;
                        z = z * s1s[f] + b1ns[f];
                        zz[rg] = fmaxf(z, 0.f);
                    }
                    uint2 st;
                    st.x = pk2(zz[0], zz[1]);
                    st.y = pk2(zz[2], zz[3]);
                    *(uint2*)(h2u + rowbase + (f0 >> 1)) = st;
                }
            }
        }
    }
}

// ---------------------------------------------------------------------------
// k2: temporal conv MFMA GEMM (M=64 fo, K=576, N=400 cols/block) + bias + BN2
//     + residual + ReLU.  Wt frags direct from global (L2); LDS = h tile only.
// ---------------------------------------------------------------------------
#define K2_SMEM 77312
__global__ __launch_bounds__(256) void k2_mfma(
    const char* __restrict__ h2b,     // bf16 bytes [n][t][w][f]
    const uint16_t* __restrict__ Abf, // Wt bf16, k0 layout
    const float* __restrict__ bt,
    const float* __restrict__ gamma2, const float* __restrict__ beta2,
    const float* __restrict__ mean2,  const float* __restrict__ var2,
    const float* __restrict__ x,      // residual
    float* __restrict__ out)
{
    extern __shared__ __align__(16) char smem2[];
    char*  lds_h = smem2;              // 76800 B
    float* s2s   = (float*)(smem2 + 76800);
    float* b2s   = s2s + 64;

    const int t0  = blockIdx.x * 16;
    const int n   = blockIdx.y;
    const int tid = threadIdx.x;

    if (tid < 64) {
        float rs = rsqrtf(var2[tid] + EPS);
        float s  = gamma2[tid] * rs;
        s2s[tid] = s;
        b2s[tid] = beta2[tid] - gamma2[tid] * mean2[tid] * rs + bt[tid] * s;
    }

    // ---- stage h tile (24 t-rows with halo), swizzled ----
    const size_t hn = (size_t)n * 300 * 3200;
    for (int c = tid; c < 4800; c += 256) {
        int rr = c >> 3, c8 = c & 7;
        int trow = rr / 25;
        int w = rr - trow * 25;
        int tg = t0 - 4 + trow;
        int4 v = make_int4(0, 0, 0, 0);
        if (tg >= 0 && tg < 300)
            v = *(const int4*)(h2b + hn + (size_t)tg * 3200 + w * 128 + (c8 << 4));
        int s = c << 4;
        *(int4*)(lds_h + (s ^ (((s >> 7) & 7) << 4))) = v;
    }
    __syncthreads();

    const int wv = tid >> 6, lane = tid & 63;
    const int l15 = lane & 15, g = lane >> 4;
    const int colbase = wv * 112;
    const int nfr = (wv == 3) ? 4 : 7;

    f32x4 acc[4][7];
    #pragma unroll
    for (int mf = 0; mf < 4; ++mf)
        #pragma unroll
        for (int nf = 0; nf < 7; ++nf)
            acc[mf][nf] = (f32x4){0.f, 0.f, 0.f, 0.f};

    for (int kk = 0; kk < 18; ++kk) {
        const int dt   = kk >> 1;
        const int half = (kk & 1) << 6;
        const int kb   = kk * 4 + g;
        bf16x8 a[4];
        #pragma unroll
        for (int mf = 0; mf < 4; ++mf)
            a[mf] = *(const bf16x8*)(Abf + (kb * 64 + l15 + mf * 16) * 8);
        #pragma unroll
        for (int nf = 0; nf < 7; ++nf) {
            if (nf < nfr) {
                int r = colbase + (nf << 4) + l15 + 25 * dt;
                int s = (r << 7) + half + (g << 4);
                bf16x8 b = *(const bf16x8*)(lds_h + (s ^ ((r & 7) << 4)));
                acc[0][nf] = __builtin_amdgcn_mfma_f32_16x16x32_bf16(a[0], b, acc[0][nf], 0, 0, 0);
                acc[1][nf] = __builtin_amdgcn_mfma_f32_16x16x32_bf16(a[1], b, acc[1][nf], 0, 0, 0);
                acc[2][nf] = __builtin_amdgcn_mfma_f32_16x16x32_bf16(a[2], b, acc[2][nf], 0, 0, 0);
                acc[3][nf] = __builtin_amdgcn_mfma_f32_16x16x32_bf16(a[3], b, acc[3][nf], 0, 0, 0);
            }
        }
    }

    const size_t outn = (size_t)n * 480000;
    #pragma unroll
    for (int mf = 0; mf < 4; ++mf) {
        #pragma unroll
        for (int nf = 0; nf < 7; ++nf) {
            if (nf < nfr) {
                int col  = colbase + (nf << 4) + l15;
                int gcol = t0 * 25 + col;
                if (gcol < 7500) {
                    #pragma unroll
                    for (int reg = 0; reg < 4; ++reg) {
                        int fo = (mf << 4) + (g << 2) + reg;
                        size_t ga = outn + (size_t)fo * 7500 + gcol;
                        float val = acc[mf][nf][reg] * s2s[fo] + b2s[fo];
                        out[ga] = fmaxf(val + x[ga], 0.f);
                    }
                }
            }
        }
    }
}

// ---------------------------------------------------------------------------
extern "C" void kernel_launch(void* const* d_in, const int* in_sizes, int n_in,
                              void* d_out, int out_size, void* d_ws, size_t ws_size,
                              hipStream_t stream) {
    const float* x      = (const float*)d_in[0];
    const float* W1     = (const float*)d_in[1];
    const float* b1     = (const float*)d_in[2];
    const float* A      = (const float*)d_in[3];
    const float* gamma1 = (const float*)d_in[4];
    const float* beta1  = (const float*)d_in[5];
    const float* mean1  = (const float*)d_in[6];
    const float* var1   = (const float*)d_in[7];
    const float* Wt     = (const float*)d_in[8];
    const float* bt     = (const float*)d_in[9];
    const float* gamma2 = (const float*)d_in[10];
    const float* beta2  = (const float*)d_in[11];
    const float* mean2  = (const float*)d_in[12];
    const float* var2   = (const float*)d_in[13];
    float* out = (float*)d_out;

    // ws layout (bytes):
    //   h2   : 0          .. 61,440,000   bf16 [64][300][25][64]
    //   At_g : 61,440,000 .. 63,283,200   bf16 [3][300][32][32]
    //   W1t  : 63,283,200 .. 63,307,776   bf16 [64][192]
    //   Abf  : 63,307,776 .. 63,381,504   bf16 Wt frags
    //   csA_g: 63,381,504 .. 63,471,504   f32  [3][7500]
    char* ws = (char*)d_ws;
    uint32_t* h2u   = (uint32_t*)ws;
    char*     h2b   = ws;
    uint16_t* At_g  = (uint16_t*)(ws + 61440000);
    uint16_t* W1t   = (uint16_t*)(ws + 63283200);
    uint16_t* Abf   = (uint16_t*)(ws + 63307776);
    float*    csA_g = (float*)   (ws + 63381504);

    hipFuncSetAttribute((const void*)k1_fused,
                        hipFuncAttributeMaxDynamicSharedMemorySize, K1_SMEM);
    hipFuncSetAttribute((const void*)k2_mfma,
                        hipFuncAttributeMaxDynamicSharedMemorySize, K2_SMEM);

    k0_prep_small<<<280, 256, 0, stream>>>(W1, Wt, A, W1t, Abf, csA_g);
    k0_prep_At<<<3600, 256, 0, stream>>>(A, At_g);
    k1_fused<<<dim3(75, 64), 256, K1_SMEM, stream>>>(
        x, At_g, W1t, csA_g, b1, gamma1, beta1, mean1, var1, h2u);
    k2_mfma<<<dim3(19, 64), 256, K2_SMEM, stream>>>(
        h2b, Abf, bt, gamma2, beta2, mean2, var2, x, out);
}

// Round 7
// 422.294 us; speedup vs baseline: 1.2298x; 1.0383x over previous
//
#include <hip/hip_runtime.h>
#include <hip/hip_bf16.h>
#include <stdint.h>

#define EPS 1e-3f

typedef __attribute__((ext_vector_type(8))) short bf16x8;
typedef __attribute__((ext_vector_type(4))) float f32x4;

__device__ inline uint32_t pk2(float a, float b) {
    __hip_bfloat162 p;
    p.x = __float2bfloat16(a);
    p.y = __float2bfloat16(b);
    return *(uint32_t*)&p;
}

// ---------------------------------------------------------------------------
// k0a: small preps.
//  W1t[f][K'] = bf16(W1[c][k*64+f]),  K' = k*64+c           (12288 elems)
//  Abf[(kb*64+fo)*8+j] = bf16(Wt[dt][fi][fo]), kb*8+j=dt*64+fi (36864 elems)
//  csA_g[k][t*25+w] = sum_v A[k][t][v][w]                    (22500 floats)
// ---------------------------------------------------------------------------
__global__ __launch_bounds__(256) void k0_prep_small(
    const float* __restrict__ W1, const float* __restrict__ Wt,
    const float* __restrict__ A,
    uint16_t* __restrict__ W1t, uint16_t* __restrict__ Abf,
    float* __restrict__ csA_g)
{
    int i = blockIdx.x * 256 + threadIdx.x;
    if (i < 12288) {
        int f = i / 192, Kp = i % 192, k = Kp >> 6, c = Kp & 63;
        __hip_bfloat16 b = __float2bfloat16(W1[c * 192 + k * 64 + f]);
        W1t[i] = *(uint16_t*)&b;
    } else if (i < 49152) {
        int j = i - 12288;
        int jj = j & 7, fo = (j >> 3) & 63, kb = j >> 9;
        int kk = kb * 8 + jj, dt = kk >> 6, fi = kk & 63;
        __hip_bfloat16 b = __float2bfloat16(Wt[(dt * 64 + fi) * 64 + fo]);
        Abf[j] = *(uint16_t*)&b;
    } else if (i < 71652) {
        int j = i - 49152;
        int k = j / 7500, r = j % 7500;
        int t = r / 25, w = r % 25;
        float s = 0.f;
        for (int v = 0; v < 25; ++v)
            s += A[((k * 300 + t) * 25 + v) * 25 + w];
        csA_g[j] = s;
    }
}

// ---------------------------------------------------------------------------
// k0b: At_g[k][t][w32][v32] = bf16(A[k][t][v][w]), zero outside v<25,w<25.
// ---------------------------------------------------------------------------
__global__ __launch_bounds__(256) void k0_prep_At(
    const float* __restrict__ A, uint16_t* __restrict__ At_g)
{
    int i = blockIdx.x * 256 + threadIdx.x;
    if (i < 921600) {
        int v = i & 31, w = (i >> 5) & 31, rest = i >> 10;
        int t = rest % 300, k = rest / 300;
        float val = 0.f;
        if (v < 25 && w < 25)
            val = A[((k * 300 + t) * 25 + v) * 25 + w];
        __hip_bfloat16 b = __float2bfloat16(val);
        At_g[i] = *(uint16_t*)&b;
    }
}

// ---------------------------------------------------------------------------
// k1_fused v3: t-tile = 4, 4 waves, 39,680 B LDS -> 4 blocks/CU (4 waves/SIMD).
//  GEMM-u A-frags loaded DIRECTLY from global x (scalar dwords, L1-shared
//  rows) -- no x staging. csA read directly from global in epilogue.
//  phase B (per wave, t = t0+wv): GEMM-u  u[c][(k,w)] = sum_v x*A_t -> U LDS
//  phase C: GEMM-z  z[f][col] = W1t . U  -> bias(csA)+BN1+ReLU -> h2 bf16.
// LDS map (bytes): U 0..38399 (100 rows x 384); s1 38400; b1n 38656;
//                  b1 38912..39679.
// ---------------------------------------------------------------------------
#define K1_SMEM 39680
__global__ __launch_bounds__(256, 4) void k1_fused(
    const float* __restrict__ x, const uint16_t* __restrict__ At_g,
    const uint16_t* __restrict__ W1t, const float* __restrict__ csA_g,
    const float* __restrict__ b1,
    const float* __restrict__ gamma1, const float* __restrict__ beta1,
    const float* __restrict__ mean1, const float* __restrict__ var1,
    uint32_t* __restrict__ h2u)
{
    extern __shared__ __align__(16) char smem[];
    float* s1s   = (float*)(smem + 38400);
    float* b1ns  = (float*)(smem + 38656);
    float* b1s   = (float*)(smem + 38912);

    const int t0   = blockIdx.x * 4;
    const int n    = blockIdx.y;
    const int tid  = threadIdx.x;
    const int lane = tid & 63, wv = tid >> 6;
    const int l15  = lane & 15, g = lane >> 4;
    const int t    = t0 + wv;                 // 75*4 = 300: no tail

    // ---- B-frags for GEMM-u (global, L2-resident) ----
    bf16x8 bfr[6];
    #pragma unroll
    for (int nf = 0; nf < 6; ++nf) {
        const int col = nf * 16 + l15;
        const int k = col >> 5, w = col & 31;
        bfr[nf] = *(const bf16x8*)(At_g + (((k * 300 + t) * 32 + w) * 32 + g * 8));
    }

    // ---- A-frags directly from x: lane reads x[n, c, t, g*8 .. g*8+7] ----
    const float* xb = x + (size_t)n * 480000 + t * 25;
    bf16x8 a[4];
    #pragma unroll
    for (int mf = 0; mf < 4; ++mf) {
        const int c = l15 + 16 * mf;
        const float* xr = xb + (size_t)c * 7500;
        union { bf16x8 v; uint32_t u[4]; } ua;
        if (g < 3) {
            const float* p = xr + g * 8;
            ua.u[0] = pk2(p[0], p[1]);
            ua.u[1] = pk2(p[2], p[3]);
            ua.u[2] = pk2(p[4], p[5]);
            ua.u[3] = pk2(p[6], p[7]);
        } else {            // v = 24 real; v = 25..31 zero (B rows zeroed too)
            ua.u[0] = pk2(xr[24], 0.f);
            ua.u[1] = 0; ua.u[2] = 0; ua.u[3] = 0;
        }
        a[mf] = ua.v;
    }

    // ---- epilogue constants (one-time, tiny) ----
    if (tid < 64) {
        float rs = rsqrtf(var1[tid] + EPS);
        s1s[tid]  = gamma1[tid] * rs;
        b1ns[tid] = beta1[tid] - gamma1[tid] * mean1[tid] * rs;
    }
    if (tid >= 64 && tid < 256) b1s[tid - 64] = b1[tid - 64];

    // ---- GEMM-u (one t per wave) ----
    f32x4 acc[4][6];
    #pragma unroll
    for (int mf = 0; mf < 4; ++mf)
        #pragma unroll
        for (int nf = 0; nf < 6; ++nf)
            acc[mf][nf] = (f32x4){0.f, 0.f, 0.f, 0.f};

    #pragma unroll
    for (int nf = 0; nf < 6; ++nf) {
        acc[0][nf] = __builtin_amdgcn_mfma_f32_16x16x32_bf16(a[0], bfr[nf], acc[0][nf], 0, 0, 0);
        acc[1][nf] = __builtin_amdgcn_mfma_f32_16x16x32_bf16(a[1], bfr[nf], acc[1][nf], 0, 0, 0);
        acc[2][nf] = __builtin_amdgcn_mfma_f32_16x16x32_bf16(a[2], bfr[nf], acc[2][nf], 0, 0, 0);
        acc[3][nf] = __builtin_amdgcn_mfma_f32_16x16x32_bf16(a[3], bfr[nf], acc[3][nf], 0, 0, 0);
    }

    // ---- write U rows (colrow = wv*25+w), swizzled ----
    #pragma unroll
    for (int nf = 0; nf < 6; ++nf) {
        const int col = nf * 16 + l15;
        const int k = col >> 5, w = col & 31;
        if (w < 25) {
            const int colrow = wv * 25 + w;
            const int sw = (w & 7) << 4;
            #pragma unroll
            for (int mf = 0; mf < 4; ++mf) {
                const int c0 = mf * 16 + g * 4;
                const int off = colrow * 384 + (((k * 64 + c0) * 2) ^ sw);
                uint2 val;
                val.x = pk2(acc[mf][nf][0], acc[mf][nf][1]);
                val.y = pk2(acc[mf][nf][2], acc[mf][nf][3]);
                *(uint2*)(smem + off) = val;
            }
        }
    }
    __syncthreads();

    // ---- GEMM-z: frags fr = wv, wv+4 (7 frags over 4 waves) ----
    int colv[2], coladdr[2], swz[2];
    const int nq = (wv < 3) ? 2 : 1;
    #pragma unroll
    for (int q = 0; q < 2; ++q) {
        int fr  = wv + 4 * q;
        int col = fr * 16 + l15;
        colv[q] = col;
        int colc = (col < 100) ? col : 99;    // clamp: keep ds_read in U region
        coladdr[q] = colc * 384;
        swz[q] = ((colc % 25) & 7) << 4;
    }

    f32x4 accz[4][2];
    #pragma unroll
    for (int mf = 0; mf < 4; ++mf)
        #pragma unroll
        for (int q = 0; q < 2; ++q)
            accz[mf][q] = (f32x4){0.f, 0.f, 0.f, 0.f};

    #pragma unroll
    for (int kb = 0; kb < 6; ++kb) {
        bf16x8 az[4];
        #pragma unroll
        for (int mf = 0; mf < 4; ++mf)
            az[mf] = *(const bf16x8*)(W1t + (l15 + 16 * mf) * 192 + kb * 32 + g * 8);
        #pragma unroll
        for (int q = 0; q < 2; ++q) {
            if (q < nq) {
                bf16x8 b = *(const bf16x8*)(smem + coladdr[q] + ((kb * 64 + g * 16) ^ swz[q]));
                accz[0][q] = __builtin_amdgcn_mfma_f32_16x16x32_bf16(az[0], b, accz[0][q], 0, 0, 0);
                accz[1][q] = __builtin_amdgcn_mfma_f32_16x16x32_bf16(az[1], b, accz[1][q], 0, 0, 0);
                accz[2][q] = __builtin_amdgcn_mfma_f32_16x16x32_bf16(az[2], b, accz[2][q], 0, 0, 0);
                accz[3][q] = __builtin_amdgcn_mfma_f32_16x16x32_bf16(az[3], b, accz[3][q], 0, 0, 0);
            }
        }
    }

    // ---- epilogue: +bias(csA direct from L2), BN1, ReLU, pack, store h2 ----
    const uint32_t hbase = (uint32_t)(n * 300 + t0) * 800;
    const int csbase = t0 * 25;
    #pragma unroll
    for (int q = 0; q < 2; ++q) {
        if (q < nq) {
            const int col = colv[q];
            if (col < 100) {
                const int trel = col / 25, w = col - trel * 25;
                const float cs0 = csA_g[csbase + col];
                const float cs1 = csA_g[7500 + csbase + col];
                const float cs2 = csA_g[15000 + csbase + col];
                const uint32_t rowbase = hbase + trel * 800 + w * 32;
                #pragma unroll
                for (int mf = 0; mf < 4; ++mf) {
                    const int f0 = mf * 16 + g * 4;
                    float zz[4];
                    #pragma unroll
                    for (int rg = 0; rg < 4; ++rg) {
                        const int f = f0 + rg;
                        float z = accz[mf][q][rg]
                                + b1s[f] * cs0 + b1s[64 + f] * cs1 + b1s[128 + f] * cs2;
                        z = z * s1s[f] + b1ns[f];
                        zz[rg] = fmaxf(z, 0.f);
                    }
                    uint2 st;
                    st.x = pk2(zz[0], zz[1]);
                    st.y = pk2(zz[2], zz[3]);
                    *(uint2*)(h2u + rowbase + (f0 >> 1)) = st;
                }
            }
        }
    }
}

// ---------------------------------------------------------------------------
// k2 v2: temporal conv MFMA GEMM, operand-SWAPPED (D[(t,w)][fo]) so the
//   epilogue is float4 x-load + float4 out-store. t-tile = 8 -> 51.2 KB LDS
//   -> 3 blocks/CU. 13 (t,w)-frags over 4 waves (4/3/3/3).
// ---------------------------------------------------------------------------
#define K2_SMEM 51712
__global__ __launch_bounds__(256, 3) void k2_mfma(
    const char* __restrict__ h2b,     // bf16 bytes [n][t][w][f]
    const uint16_t* __restrict__ Abf, // Wt bf16, k0 layout
    const float* __restrict__ bt,
    const float* __restrict__ gamma2, const float* __restrict__ beta2,
    const float* __restrict__ mean2,  const float* __restrict__ var2,
    const float* __restrict__ x,      // residual
    float* __restrict__ out)
{
    extern __shared__ __align__(16) char smem2[];
    char*  lds_h = smem2;              // 51200 B: 400 rows (16t x 25w) x 128 B
    float* s2s   = (float*)(smem2 + 51200);
    float* b2s   = s2s + 64;

    const int t0  = blockIdx.x * 8;
    const int n   = blockIdx.y;
    const int tid = threadIdx.x;

    if (tid < 64) {
        float rs = rsqrtf(var2[tid] + EPS);
        float s  = gamma2[tid] * rs;
        s2s[tid] = s;
        b2s[tid] = beta2[tid] - gamma2[tid] * mean2[tid] * rs + bt[tid] * s;
    }

    // ---- stage h tile (16 t-rows with halo t0-4..t0+11), swizzled ----
    const size_t hn = (size_t)n * 300 * 3200;
    for (int c = tid; c < 3200; c += 256) {
        int rr = c >> 3, c8 = c & 7;
        int trow = rr / 25;
        int w = rr - trow * 25;
        int tg = t0 - 4 + trow;
        int4 v = make_int4(0, 0, 0, 0);
        if (tg >= 0 && tg < 300)
            v = *(const int4*)(h2b + hn + (size_t)tg * 3200 + w * 128 + (c8 << 4));
        int s = c << 4;
        *(int4*)(lds_h + (s ^ (((s >> 7) & 7) << 4))) = v;
    }
    __syncthreads();

    const int wv = tid >> 6, lane = tid & 63;
    const int l15 = lane & 15, g = lane >> 4;
    const int nMf = (wv == 0) ? 4 : 3;        // frags q*4+wv; frag 12 -> wave 0

    int rbase[4];
    #pragma unroll
    for (int q = 0; q < 4; ++q) {
        int col = (q * 4 + wv) * 16 + l15;
        rbase[q] = (col < 200) ? col : 199;   // clamp keeps LDS reads in range
    }

    f32x4 acc[4][4];
    #pragma unroll
    for (int q = 0; q < 4; ++q)
        #pragma unroll
        for (int mf = 0; mf < 4; ++mf)
            acc[q][mf] = (f32x4){0.f, 0.f, 0.f, 0.f};

    for (int kk = 0; kk < 18; ++kk) {
        const int dt   = kk >> 1;
        const int half = (kk & 1) << 6;
        const int kb   = kk * 4 + g;
        bf16x8 wfr[4];
        #pragma unroll
        for (int mf = 0; mf < 4; ++mf)
            wfr[mf] = *(const bf16x8*)(Abf + (kb * 64 + l15 + mf * 16) * 8);
        #pragma unroll
        for (int q = 0; q < 4; ++q) {
            if (q < nMf) {
                int r = rbase[q] + 25 * dt;
                int s = (r << 7) + half + (g << 4);
                bf16x8 hfr = *(const bf16x8*)(lds_h + (s ^ ((r & 7) << 4)));
                acc[q][0] = __builtin_amdgcn_mfma_f32_16x16x32_bf16(hfr, wfr[0], acc[q][0], 0, 0, 0);
                acc[q][1] = __builtin_amdgcn_mfma_f32_16x16x32_bf16(hfr, wfr[1], acc[q][1], 0, 0, 0);
                acc[q][2] = __builtin_amdgcn_mfma_f32_16x16x32_bf16(hfr, wfr[2], acc[q][2], 0, 0, 0);
                acc[q][3] = __builtin_amdgcn_mfma_f32_16x16x32_bf16(hfr, wfr[3], acc[q][3], 0, 0, 0);
            }
        }
    }

    // ---- epilogue: lane holds 4 consecutive (t,w) cols for fo = mf*16+l15 ----
    const size_t outn = (size_t)n * 480000;
    const int base = t0 * 25;
    const int vcols = (7500 - base < 200) ? (7500 - base) : 200;
    #pragma unroll
    for (int q = 0; q < 4; ++q) {
        if (q < nMf) {
            const int col0 = (q * 4 + wv) * 16 + g * 4;
            if (col0 < vcols) {
                #pragma unroll
                for (int mf = 0; mf < 4; ++mf) {
                    const int fo = mf * 16 + l15;
                    const size_t ga = outn + (size_t)fo * 7500 + base + col0;
                    const float4 xr = *(const float4*)(x + ga);
                    const float s2 = s2s[fo], b2 = b2s[fo];
                    float4 o;
                    o.x = fmaxf(acc[q][mf][0] * s2 + b2 + xr.x, 0.f);
                    o.y = fmaxf(acc[q][mf][1] * s2 + b2 + xr.y, 0.f);
                    o.z = fmaxf(acc[q][mf][2] * s2 + b2 + xr.z, 0.f);
                    o.w = fmaxf(acc[q][mf][3] * s2 + b2 + xr.w, 0.f);
                    *(float4*)(out + ga) = o;
                }
            }
        }
    }
}

// ---------------------------------------------------------------------------
extern "C" void kernel_launch(void* const* d_in, const int* in_sizes, int n_in,
                              void* d_out, int out_size, void* d_ws, size_t ws_size,
                              hipStream_t stream) {
    const float* x      = (const float*)d_in[0];
    const float* W1     = (const float*)d_in[1];
    const float* b1     = (const float*)d_in[2];
    const float* A      = (const float*)d_in[3];
    const float* gamma1 = (const float*)d_in[4];
    const float* beta1  = (const float*)d_in[5];
    const float* mean1  = (const float*)d_in[6];
    const float* var1   = (const float*)d_in[7];
    const float* Wt     = (const float*)d_in[8];
    const float* bt     = (const float*)d_in[9];
    const float* gamma2 = (const float*)d_in[10];
    const float* beta2  = (const float*)d_in[11];
    const float* mean2  = (const float*)d_in[12];
    const float* var2   = (const float*)d_in[13];
    float* out = (float*)d_out;

    // ws layout (bytes):
    //   h2   : 0          .. 61,440,000   bf16 [64][300][25][64]
    //   At_g : 61,440,000 .. 63,283,200   bf16 [3][300][32][32]
    //   W1t  : 63,283,200 .. 63,307,776   bf16 [64][192]
    //   Abf  : 63,307,776 .. 63,381,504   bf16 Wt frags
    //   csA_g: 63,381,504 .. 63,471,504   f32  [3][7500]
    char* ws = (char*)d_ws;
    uint32_t* h2u   = (uint32_t*)ws;
    char*     h2b   = ws;
    uint16_t* At_g  = (uint16_t*)(ws + 61440000);
    uint16_t* W1t   = (uint16_t*)(ws + 63283200);
    uint16_t* Abf   = (uint16_t*)(ws + 63307776);
    float*    csA_g = (float*)   (ws + 63381504);

    hipFuncSetAttribute((const void*)k1_fused,
                        hipFuncAttributeMaxDynamicSharedMemorySize, K1_SMEM);
    hipFuncSetAttribute((const void*)k2_mfma,
                        hipFuncAttributeMaxDynamicSharedMemorySize, K2_SMEM);

    k0_prep_small<<<280, 256, 0, stream>>>(W1, Wt, A, W1t, Abf, csA_g);
    k0_prep_At<<<3600, 256, 0, stream>>>(A, At_g);
    k1_fused<<<dim3(75, 64), 256, K1_SMEM, stream>>>(
        x, At_g, W1t, csA_g, b1, gamma1, beta1, mean1, var1, h2u);
    k2_mfma<<<dim3(38, 64), 256, K2_SMEM, stream>>>(
        h2b, Abf, bt, gamma2, beta2, mean2, var2, x, out);
}